// Round 1
// baseline (797.850 us; speedup 1.0000x reference)
//
#include <hip/hip_runtime.h>

#define BB 8
#define NN 2048
#define FF 64
#define HH 32
#define SPLIT 8   // grid-level K split; total K split = SPLIT * 4 waves = 32

static __device__ __forceinline__ float warp_sum64(float v) {
  for (int off = 32; off; off >>= 1) v += __shfl_down(v, off, 64);
  return v;
}

// d_i = rowsum(a) + add_i ; dm = d^-1/2 ; add_i = (|a_ii| < 1e-7)
__global__ __launch_bounds__(256) void deg_kernel(const float* __restrict__ A,
                                                  float* __restrict__ dm,
                                                  float* __restrict__ addf) {
  const int lane = threadIdx.x & 63;
  const int w = threadIdx.x >> 6;
  const size_t row = (size_t)blockIdx.x * 4 + w;  // flat b*N + n
  const size_t n = row & (NN - 1);
  const float* Ar = A + row * (size_t)NN;
  float sum = 0.f;
#pragma unroll
  for (int it = 0; it < 8; ++it) {
    float4 v = *(const float4*)(Ar + it * 256 + lane * 4);
    sum += v.x + v.y + v.z + v.w;
  }
  sum = warp_sum64(sum);
  if (lane == 0) {
    const float diag = Ar[n];
    const float ad = (fabsf(diag) < 1e-7f) ? 1.f : 0.f;
    dm[row] = 1.f / sqrtf(sum + ad);
    addf[row] = ad;
  }
}

// hs1[row][f] = dm_row * sum_c x[row][c] * W1[c][f]
__global__ __launch_bounds__(256) void xw_kernel(const float* __restrict__ x,
                                                 const float* __restrict__ W1,
                                                 const float* __restrict__ dm,
                                                 float* __restrict__ hs) {
  __shared__ float xs[8][FF + 1];
  __shared__ float wl[FF * HH];
  const int tid = threadIdx.x;
  const size_t row0 = (size_t)blockIdx.x * 8;
  for (int k = tid; k < FF * HH; k += 256) wl[k] = W1[k];
  for (int k = tid; k < 8 * FF; k += 256) xs[k >> 6][k & 63] = x[row0 * FF + k];
  __syncthreads();
  const int r = tid >> 5, c = tid & 31;
  float acc = 0.f;
#pragma unroll
  for (int k = 0; k < FF; ++k) acc = fmaf(xs[r][k], wl[k * HH + c], acc);
  const size_t row = row0 + r;
  hs[row * HH + c] = dm[row] * acc;
}

// partial[s][row][f] = sum_{j in K-range} a[row][j] * hs[j][f]
// block = 4 waves; wave handles 64 rows x 32 f over 64 j; lane <-> row
__global__ __launch_bounds__(256) void mm_kernel(const float* __restrict__ A,
                                                 const float* __restrict__ hs,
                                                 float* __restrict__ part) {
  const int bk = blockIdx.x;
  const int s = bk & (SPLIT - 1);
  const int rb = (bk >> 3) & 31;
  const int b = bk >> 8;
  const int lane = threadIdx.x & 63;
  const int w = __builtin_amdgcn_readfirstlane(threadIdx.x >> 6);
  const int row = rb * 64 + lane;
  const int j0 = s * 256 + w * 64;
  const float* __restrict__ Arow = A + ((size_t)b * NN + row) * NN;
  const float* __restrict__ hsb = hs + (size_t)b * NN * HH;
  float acc[HH];
#pragma unroll
  for (int f = 0; f < HH; ++f) acc[f] = 0.f;
  for (int j = j0; j < j0 + 64; j += 4) {
    const float4 av = *(const float4*)(Arow + j);
    const float* __restrict__ hr = hsb + (size_t)j * HH;  // wave-uniform address
    const float a0 = av.x, a1 = av.y, a2 = av.z, a3 = av.w;
#pragma unroll
    for (int f = 0; f < HH; ++f) {
      acc[f] = fmaf(a0, hr[f], acc[f]);
      acc[f] = fmaf(a1, hr[HH + f], acc[f]);
      acc[f] = fmaf(a2, hr[2 * HH + f], acc[f]);
      acc[f] = fmaf(a3, hr[3 * HH + f], acc[f]);
    }
  }
  // cross-wave reduction of the 4 K-subranges
  __shared__ float red[4 * 64 * 33];
  float* my = &red[(w * 64 + lane) * 33];
#pragma unroll
  for (int f = 0; f < HH; ++f) my[f] = acc[f];
  __syncthreads();
  const int f = threadIdx.x & 31;
  const int l0 = threadIdx.x >> 5;
  float* __restrict__ outp =
      part + ((size_t)s * BB * NN + (size_t)b * NN + rb * 64) * HH;
#pragma unroll
  for (int l8 = 0; l8 < 8; ++l8) {
    const int l = l0 + l8 * 8;
    outp[l * HH + f] = red[l * 33 + f] + red[(64 + l) * 33 + f] +
                       red[(128 + l) * 33 + f] + red[(192 + l) * 33 + f];
  }
}

// h = relu(dm_i*(sum_s part + add_i*hs_prev_i) + bias)
// then either hs_next = dm_i * (h @ Wn)   (do_pool=0)
//        or   gmax[b][c] = max(gmax, h)   (do_pool=1, uint atomicMax, h>=0)
__global__ __launch_bounds__(256) void reduce_kernel(const float* __restrict__ part,
                                                     const float* __restrict__ hs_prev,
                                                     const float* __restrict__ dm,
                                                     const float* __restrict__ addf,
                                                     const float* __restrict__ bias,
                                                     const float* __restrict__ Wn,
                                                     float* __restrict__ hs_next,
                                                     unsigned int* __restrict__ gmax,
                                                     const int do_pool) {
  __shared__ float hrow[8][HH + 1];
  __shared__ float wl[HH * HH];
  const int tid = threadIdx.x;
  if (!do_pool)
    for (int k = tid; k < HH * HH; k += 256) wl[k] = Wn[k];
  const int r = tid >> 5, c = tid & 31;
  const size_t row = (size_t)blockIdx.x * 8 + r;
  float psum = 0.f;
#pragma unroll
  for (int s = 0; s < SPLIT; ++s)
    psum += part[((size_t)s * BB * NN + row) * HH + c];
  const float dmv = dm[row];
  float h = fmaf(dmv, psum + addf[row] * hs_prev[row * HH + c], bias[c]);
  h = fmaxf(h, 0.f);
  if (do_pool) {
    const int b = (int)(row >> 11);  // N = 2048
    atomicMax(&gmax[b * HH + c], __float_as_uint(h));
  } else {
    hrow[r][c] = h;
    __syncthreads();
    float acc = 0.f;
#pragma unroll
    for (int k = 0; k < HH; ++k) acc = fmaf(hrow[r][k], wl[k * HH + c], acc);
    hs_next[row * HH + c] = dmv * acc;
  }
}

// out[b] = (relu(g @ Wf1 + bf1)) @ Wf2 + bf2 ; one wave per batch
__global__ __launch_bounds__(64) void head_kernel(const unsigned int* __restrict__ gmax,
                                                  const float* __restrict__ Wf1,
                                                  const float* __restrict__ bf1,
                                                  const float* __restrict__ Wf2,
                                                  const float* __restrict__ bf2,
                                                  float* __restrict__ out) {
  const int b = blockIdx.x;
  const int t = threadIdx.x;  // 0..63 hidden units
  float acc = bf1[t];
#pragma unroll
  for (int c = 0; c < HH; ++c)
    acc = fmaf(__uint_as_float(gmax[b * HH + c]), Wf1[c * (2 * HH) + t], acc);
  acc = fmaxf(acc, 0.f);
  float v = acc * Wf2[t];
  v = warp_sum64(v);
  if (t == 0) out[b] = v + bf2[0];
}

extern "C" void kernel_launch(void* const* d_in, const int* in_sizes, int n_in,
                              void* d_out, int out_size, void* d_ws, size_t ws_size,
                              hipStream_t stream) {
  const float* x   = (const float*)d_in[0];
  const float* a   = (const float*)d_in[1];
  const float* W1  = (const float*)d_in[2];
  const float* b1  = (const float*)d_in[3];
  const float* W2  = (const float*)d_in[4];
  const float* b2  = (const float*)d_in[5];
  const float* W3  = (const float*)d_in[6];
  const float* b3  = (const float*)d_in[7];
  const float* Wf1 = (const float*)d_in[8];
  const float* bf1 = (const float*)d_in[9];
  const float* Wf2 = (const float*)d_in[10];
  const float* bf2 = (const float*)d_in[11];
  float* out = (float*)d_out;

  float* ws = (float*)d_ws;
  const size_t BN = (size_t)BB * NN;  // 16384
  float* dm   = ws;                    // 16384
  float* addf = dm + BN;               // 16384
  float* hs_a = addf + BN;             // BN*32
  float* hs_b = hs_a + BN * HH;        // BN*32
  float* part = hs_b + BN * HH;        // SPLIT*BN*32 (~16.8 MB)
  unsigned int* gmax = (unsigned int*)(part + (size_t)SPLIT * BN * HH);
  // total ws use ~21.1 MB

  hipMemsetAsync(gmax, 0, BB * HH * sizeof(unsigned int), stream);

  deg_kernel<<<BN / 4, 256, 0, stream>>>(a, dm, addf);
  xw_kernel<<<BN / 8, 256, 0, stream>>>(x, W1, dm, hs_a);

  mm_kernel<<<BB * 32 * SPLIT, 256, 0, stream>>>(a, hs_a, part);
  reduce_kernel<<<BN / 8, 256, 0, stream>>>(part, hs_a, dm, addf, b1, W2, hs_b, nullptr, 0);

  mm_kernel<<<BB * 32 * SPLIT, 256, 0, stream>>>(a, hs_b, part);
  reduce_kernel<<<BN / 8, 256, 0, stream>>>(part, hs_b, dm, addf, b2, W3, hs_a, nullptr, 0);

  mm_kernel<<<BB * 32 * SPLIT, 256, 0, stream>>>(a, hs_a, part);
  reduce_kernel<<<BN / 8, 256, 0, stream>>>(part, hs_a, dm, addf, b3, nullptr, nullptr, gmax, 1);

  head_kernel<<<BB, 64, 0, stream>>>(gmax, Wf1, bf1, Wf2, bf2, out);
}

// Round 2
// 506.750 us; speedup vs baseline: 1.5744x; 1.5744x over previous
//
#include <hip/hip_runtime.h>

#define BB 8
#define NN 2048
#define FF 64
#define HH 32
#define SPLIT 8   // grid-level K split; total K split = SPLIT * 4 waves = 32

static __device__ __forceinline__ float warp_sum64(float v) {
  for (int off = 32; off; off >>= 1) v += __shfl_down(v, off, 64);
  return v;
}

static __device__ __forceinline__ unsigned int f2bf_rne(float f) {
  unsigned int u = __float_as_uint(f);
  return (u + 0x7fffu + ((u >> 16) & 1u)) >> 16;
}

#define B2F_LO(u) __uint_as_float((u) << 16)
#define B2F_HI(u) __uint_as_float((u) & 0xffff0000u)

// d_i = rowsum(a) + add_i ; dm = d^-1/2 ; add_i = (|a_ii| < 1e-7)
// Also converts A to bf16 (RNE) into Abf, fused with the mandatory read.
__global__ __launch_bounds__(256) void deg_cvt_kernel(const float* __restrict__ A,
                                                      float* __restrict__ dm,
                                                      float* __restrict__ addf,
                                                      unsigned short* __restrict__ Abf) {
  const int lane = threadIdx.x & 63;
  const int w = threadIdx.x >> 6;
  const size_t row = (size_t)blockIdx.x * 4 + w;  // flat b*N + n
  const size_t n = row & (NN - 1);
  const float* Ar = A + row * (size_t)NN;
  unsigned int* Abr = (unsigned int*)(Abf + row * (size_t)NN);  // 2 bf16 per uint
  float sum = 0.f;
#pragma unroll
  for (int it = 0; it < 8; ++it) {
    float4 v = *(const float4*)(Ar + it * 256 + lane * 4);
    sum += v.x + v.y + v.z + v.w;
    uint2 p;
    p.x = f2bf_rne(v.x) | (f2bf_rne(v.y) << 16);
    p.y = f2bf_rne(v.z) | (f2bf_rne(v.w) << 16);
    *(uint2*)(Abr + it * 128 + lane * 2) = p;
  }
  sum = warp_sum64(sum);
  if (lane == 0) {
    const float diag = Ar[n];
    const float ad = (fabsf(diag) < 1e-7f) ? 1.f : 0.f;
    dm[row] = 1.f / sqrtf(sum + ad);
    addf[row] = ad;
  }
}

// hs1[row][f] = dm_row * sum_c x[row][c] * W1[c][f]
__global__ __launch_bounds__(256) void xw_kernel(const float* __restrict__ x,
                                                 const float* __restrict__ W1,
                                                 const float* __restrict__ dm,
                                                 float* __restrict__ hs) {
  __shared__ float xs[8][FF + 1];
  __shared__ float wl[FF * HH];
  const int tid = threadIdx.x;
  const size_t row0 = (size_t)blockIdx.x * 8;
  for (int k = tid; k < FF * HH; k += 256) wl[k] = W1[k];
  for (int k = tid; k < 8 * FF; k += 256) xs[k >> 6][k & 63] = x[row0 * FF + k];
  __syncthreads();
  const int r = tid >> 5, c = tid & 31;
  float acc = 0.f;
#pragma unroll
  for (int k = 0; k < FF; ++k) acc = fmaf(xs[r][k], wl[k * HH + c], acc);
  const size_t row = row0 + r;
  hs[row * HH + c] = dm[row] * acc;
}

// partial[s][row][f] = sum_{j in K-range} a[row][j] * hs[j][f]
// block = 4 waves; wave handles 64 rows x 32 f over 64 j; lane <-> row.
// A is bf16; each lane preloads its ENTIRE 128 B K-slice up front so every
// fetched cache line is fully consumed immediately (no L2 reuse window).
__global__ __launch_bounds__(256) void mm_kernel(const unsigned short* __restrict__ Abf,
                                                 const float* __restrict__ hs,
                                                 float* __restrict__ part) {
  const int bk = blockIdx.x;
  const int s = bk & (SPLIT - 1);
  const int rb = (bk >> 3) & 31;
  const int b = bk >> 8;
  const int lane = threadIdx.x & 63;
  const int w = __builtin_amdgcn_readfirstlane(threadIdx.x >> 6);
  const int row = rb * 64 + lane;
  const int j0 = s * 256 + w * 64;
  const uint4* __restrict__ Aptr =
      (const uint4*)(Abf + ((size_t)b * NN + row) * NN + j0);
  const float* __restrict__ hsb = hs + (size_t)b * NN * HH;

  uint4 adata[8];  // 64 bf16 = lane's whole K-slice, 128 B contiguous
#pragma unroll
  for (int c = 0; c < 8; ++c) adata[c] = Aptr[c];

  float acc[HH];
#pragma unroll
  for (int f = 0; f < HH; ++f) acc[f] = 0.f;

#pragma unroll
  for (int c = 0; c < 8; ++c) {
    float av[8];
    av[0] = B2F_LO(adata[c].x); av[1] = B2F_HI(adata[c].x);
    av[2] = B2F_LO(adata[c].y); av[3] = B2F_HI(adata[c].y);
    av[4] = B2F_LO(adata[c].z); av[5] = B2F_HI(adata[c].z);
    av[6] = B2F_LO(adata[c].w); av[7] = B2F_HI(adata[c].w);
    const float* __restrict__ hr = hsb + (size_t)(j0 + c * 8) * HH;  // uniform
#pragma unroll
    for (int jj = 0; jj < 8; ++jj) {
#pragma unroll
      for (int f = 0; f < HH; ++f)
        acc[f] = fmaf(av[jj], hr[jj * HH + f], acc[f]);
    }
  }

  // cross-wave reduction of the 4 K-subranges
  __shared__ float red[4 * 64 * 33];
  float* my = &red[(w * 64 + lane) * 33];
#pragma unroll
  for (int f = 0; f < HH; ++f) my[f] = acc[f];
  __syncthreads();
  const int f = threadIdx.x & 31;
  const int l0 = threadIdx.x >> 5;
  float* __restrict__ outp =
      part + ((size_t)s * BB * NN + (size_t)b * NN + rb * 64) * HH;
#pragma unroll
  for (int l8 = 0; l8 < 8; ++l8) {
    const int l = l0 + l8 * 8;
    outp[l * HH + f] = red[l * 33 + f] + red[(64 + l) * 33 + f] +
                       red[(128 + l) * 33 + f] + red[(192 + l) * 33 + f];
  }
}

// h = relu(dm_i*(sum_s part + add_i*hs_prev_i) + bias)
// then either hs_next = dm_i * (h @ Wn)   (do_pool=0)
//        or   gmax[b][c] = max(gmax, h)   (do_pool=1, uint atomicMax, h>=0)
__global__ __launch_bounds__(256) void reduce_kernel(const float* __restrict__ part,
                                                     const float* __restrict__ hs_prev,
                                                     const float* __restrict__ dm,
                                                     const float* __restrict__ addf,
                                                     const float* __restrict__ bias,
                                                     const float* __restrict__ Wn,
                                                     float* __restrict__ hs_next,
                                                     unsigned int* __restrict__ gmax,
                                                     const int do_pool) {
  __shared__ float hrow[8][HH + 1];
  __shared__ float wl[HH * HH];
  const int tid = threadIdx.x;
  if (!do_pool)
    for (int k = tid; k < HH * HH; k += 256) wl[k] = Wn[k];
  const int r = tid >> 5, c = tid & 31;
  const size_t row = (size_t)blockIdx.x * 8 + r;
  float psum = 0.f;
#pragma unroll
  for (int s = 0; s < SPLIT; ++s)
    psum += part[((size_t)s * BB * NN + row) * HH + c];
  const float dmv = dm[row];
  float h = fmaf(dmv, psum + addf[row] * hs_prev[row * HH + c], bias[c]);
  h = fmaxf(h, 0.f);
  if (do_pool) {
    const int b = (int)(row >> 11);  // N = 2048
    atomicMax(&gmax[b * HH + c], __float_as_uint(h));
  } else {
    hrow[r][c] = h;
    __syncthreads();
    float acc = 0.f;
#pragma unroll
    for (int k = 0; k < HH; ++k) acc = fmaf(hrow[r][k], wl[k * HH + c], acc);
    hs_next[row * HH + c] = dmv * acc;
  }
}

// out[b] = (relu(g @ Wf1 + bf1)) @ Wf2 + bf2 ; one wave per batch
__global__ __launch_bounds__(64) void head_kernel(const unsigned int* __restrict__ gmax,
                                                  const float* __restrict__ Wf1,
                                                  const float* __restrict__ bf1,
                                                  const float* __restrict__ Wf2,
                                                  const float* __restrict__ bf2,
                                                  float* __restrict__ out) {
  const int b = blockIdx.x;
  const int t = threadIdx.x;  // 0..63 hidden units
  float acc = bf1[t];
#pragma unroll
  for (int c = 0; c < HH; ++c)
    acc = fmaf(__uint_as_float(gmax[b * HH + c]), Wf1[c * (2 * HH) + t], acc);
  acc = fmaxf(acc, 0.f);
  float v = acc * Wf2[t];
  v = warp_sum64(v);
  if (t == 0) out[b] = v + bf2[0];
}

extern "C" void kernel_launch(void* const* d_in, const int* in_sizes, int n_in,
                              void* d_out, int out_size, void* d_ws, size_t ws_size,
                              hipStream_t stream) {
  const float* x   = (const float*)d_in[0];
  const float* a   = (const float*)d_in[1];
  const float* W1  = (const float*)d_in[2];
  const float* b1  = (const float*)d_in[3];
  const float* W2  = (const float*)d_in[4];
  const float* b2  = (const float*)d_in[5];
  const float* W3  = (const float*)d_in[6];
  const float* b3  = (const float*)d_in[7];
  const float* Wf1 = (const float*)d_in[8];
  const float* bf1 = (const float*)d_in[9];
  const float* Wf2 = (const float*)d_in[10];
  const float* bf2 = (const float*)d_in[11];
  float* out = (float*)d_out;

  float* ws = (float*)d_ws;
  const size_t BN = (size_t)BB * NN;  // 16384
  float* dm   = ws;                    // 16384
  float* addf = dm + BN;               // 16384
  float* hs_a = addf + BN;             // BN*32
  float* hs_b = hs_a + BN * HH;        // BN*32
  float* part = hs_b + BN * HH;        // SPLIT*BN*32 (~16.8 MB)
  unsigned int* gmax = (unsigned int*)(part + (size_t)SPLIT * BN * HH);
  unsigned short* Abf = (unsigned short*)(gmax + BB * HH);  // 67 MB bf16 A
  // total ws use ~88 MB

  hipMemsetAsync(gmax, 0, BB * HH * sizeof(unsigned int), stream);

  deg_cvt_kernel<<<BN / 4, 256, 0, stream>>>(a, dm, addf, Abf);
  xw_kernel<<<BN / 8, 256, 0, stream>>>(x, W1, dm, hs_a);

  mm_kernel<<<BB * 32 * SPLIT, 256, 0, stream>>>(Abf, hs_a, part);
  reduce_kernel<<<BN / 8, 256, 0, stream>>>(part, hs_a, dm, addf, b1, W2, hs_b, nullptr, 0);

  mm_kernel<<<BB * 32 * SPLIT, 256, 0, stream>>>(Abf, hs_b, part);
  reduce_kernel<<<BN / 8, 256, 0, stream>>>(part, hs_b, dm, addf, b2, W3, hs_a, nullptr, 0);

  mm_kernel<<<BB * 32 * SPLIT, 256, 0, stream>>>(Abf, hs_a, part);
  reduce_kernel<<<BN / 8, 256, 0, stream>>>(part, hs_a, dm, addf, b3, nullptr, nullptr, gmax, 1);

  head_kernel<<<BB, 64, 0, stream>>>(gmax, Wf1, bf1, Wf2, bf2, out);
}